// Round 1
// 182.024 us; speedup vs baseline: 1.4653x; 1.4653x over previous
//
#include <hip/hip_runtime.h>

// Problem constants
#define BB 256   // batch
#define HH 512   // hidden
#define CC 64    // spline channels
#define NN 100   // time knots
#define KT 8     // K_TERMS

typedef short s16x8 __attribute__((ext_vector_type(8)));
typedef float f32x4 __attribute__((ext_vector_type(4)));

#define MFMA16(a, b, c) __builtin_amdgcn_mfma_f32_16x16x32_bf16((a), (b), (c), 0, 0, 0)

static __device__ __forceinline__ unsigned short f2bf(float f) {
    union { float f; unsigned int u; } v; v.f = f;
    unsigned int r = v.u + 0x7FFFu + ((v.u >> 16) & 1u);  // RNE
    return (unsigned short)(r >> 16);
}

// ---------------------------------------------------------------------------
// A-frag layout for a 16-row x 512-col bf16 activation tile t (8192 halfwords):
//   F[t*8192 + g*512 + lane*8 + e] = M[lane&15][g*32 + (lane>>4)*8 + e]
// MFMA A-operand for Ktile g is then a coalesced 16B/lane load at lane*8.
// ---------------------------------------------------------------------------

// ---------------------------------------------------------------------------
// k_pack: weight bf16 conversion into MFMA-frag-packed layout + h conversion +
// cubic spline evaluation (x, xdot) + zero the sync counters.
// ---------------------------------------------------------------------------
__global__ void k_pack(const float* __restrict__ wh, const float* __restrict__ wout,
                       const float* __restrict__ wx, const float* __restrict__ h,
                       const float* __restrict__ coeffs, const float* __restrict__ dcoeffs,
                       const float* __restrict__ tobs, const float* __restrict__ tg,
                       unsigned short* __restrict__ whp, unsigned short* __restrict__ wop,
                       unsigned short* __restrict__ wxp, unsigned short* __restrict__ hb,
                       unsigned short* __restrict__ xb, unsigned short* __restrict__ xdb,
                       unsigned int* __restrict__ cnt) {
    int gid = blockIdx.x * 256 + threadIdx.x;
    if (gid < 524288) {                       // wh / wout packed (262144 each)
        const float* src = (gid < 262144) ? wh : wout;
        unsigned short* dst = (gid < 262144) ? whp : wop;
        int p = gid & 262143;
        int e = p & 7, lane = (p >> 3) & 63, g = (p >> 9) & 15, cg = (p >> 13) & 1, w = p >> 14;
        int row = w * 32 + cg * 16 + (lane & 15);
        int k = g * 32 + (lane >> 4) * 8 + e;
        dst[p] = f2bf(src[row * HH + k]);
    } else if (gid < 557056) {                // wx packed (32768)
        int p = gid - 524288;
        int e = p & 7, lane = (p >> 3) & 63, g = (p >> 9) & 1, cg = (p >> 10) & 1, w = p >> 11;
        int row = w * 32 + cg * 16 + (lane & 15);
        int k = g * 32 + (lane >> 4) * 8 + e;
        wxp[p] = f2bf(wx[row * CC + k]);
    } else if (gid < 688128) {                // h -> bf16 row-major (131072)
        int p = gid - 557056;
        hb[p] = f2bf(h[p]);
    } else if (gid < 704512) {                // spline eval: x, xdot (16384)
        int p = gid - 688128;
        int b = p >> 6, c = p & 63;
        float t = tg[0];
        int cntv = 0;
        for (int n = 0; n < NN; n++) cntv += (tobs[n] <= t) ? 1 : 0;
        int idx = cntv - 1;
        idx = idx < 0 ? 0 : (idx > NN - 2 ? NN - 2 : idx);  // clip to [0, 98]
        float dt = t - tobs[idx];
        const float* cb = coeffs + ((size_t)(b * (NN - 1) + idx) * 4) * CC + c;
        float xv = cb[0] + dt * (cb[CC] + dt * (cb[2 * CC] + dt * cb[3 * CC]));
        const float* db = dcoeffs + ((size_t)(b * (NN - 1) + idx) * 4) * CC + c;
        float xd = db[0] + dt * (db[CC] + dt * (db[2 * CC] + dt * db[3 * CC]));
        xb[p] = f2bf(xv);
        xdb[p] = f2bf(xd);
    } else if (gid < 704768) {                // zero sync counters (256 words)
        cnt[gid - 704512] = 0u;
    }
}

// ---------------------------------------------------------------------------
// k_l1: l1 = x@wx^T + h@wh^T + b0 -> relu(bf16), drelu=sigmoid(l1) (f32)
//       fused: v = xdot@wx^T ; s0 = drelu*v (bf16)
// ---------------------------------------------------------------------------
__global__ void k_l1(const unsigned short* __restrict__ whp, const unsigned short* __restrict__ wxp,
                     const unsigned short* __restrict__ hb, const unsigned short* __restrict__ xb,
                     const unsigned short* __restrict__ xdb, const float* __restrict__ b0g,
                     unsigned short* __restrict__ relu_b, float* __restrict__ drelu_f,
                     unsigned short* __restrict__ s0_b) {
    __shared__ unsigned short sh[32][520];
    __shared__ unsigned short sx[32][72];
    __shared__ unsigned short sxd[32][72];
    int tid = threadIdx.x;
    int b0 = blockIdx.x * 32;
    int it = blockIdx.y;
    for (int idx = tid; idx < 32 * 64; idx += 256) {
        int r = idx >> 6, c8 = idx & 63;
        *(int4*)&sh[r][c8 * 8] = *(const int4*)&hb[(b0 + r) * HH + c8 * 8];
    }
    for (int idx = tid; idx < 32 * 8; idx += 256) {
        int r = idx >> 3, c8 = idx & 7;
        *(int4*)&sx[r][c8 * 8] = *(const int4*)&xb[(b0 + r) * CC + c8 * 8];
        *(int4*)&sxd[r][c8 * 8] = *(const int4*)&xdb[(b0 + r) * CC + c8 * 8];
    }
    __syncthreads();
    int wv = tid >> 6, lane = tid & 63, col = lane & 15, kq = lane >> 4;
    int isub = it * 64 + wv * 16;
    int wpk = isub >> 5, cg = (isub >> 4) & 1;
    f32x4 acc0 = {0.f, 0.f, 0.f, 0.f}, acc1 = {0.f, 0.f, 0.f, 0.f};
    f32x4 vac0 = {0.f, 0.f, 0.f, 0.f}, vac1 = {0.f, 0.f, 0.f, 0.f};
    const s16x8* whfrag = (const s16x8*)whp + (size_t)((wpk * 2 + cg) * 16) * 64 + lane;
#pragma unroll
    for (int g = 0; g < 16; g++) {
        s16x8 bf = whfrag[g * 64];
        s16x8 a0 = *(const s16x8*)&sh[col][g * 32 + kq * 8];
        s16x8 a1 = *(const s16x8*)&sh[16 + col][g * 32 + kq * 8];
        acc0 = MFMA16(a0, bf, acc0);
        acc1 = MFMA16(a1, bf, acc1);
    }
    const s16x8* wxfrag = (const s16x8*)wxp + (size_t)((wpk * 2 + cg) * 2) * 64 + lane;
#pragma unroll
    for (int g = 0; g < 2; g++) {
        s16x8 bf = wxfrag[g * 64];
        s16x8 a0 = *(const s16x8*)&sx[col][g * 32 + kq * 8];
        s16x8 a1 = *(const s16x8*)&sx[16 + col][g * 32 + kq * 8];
        acc0 = MFMA16(a0, bf, acc0);
        acc1 = MFMA16(a1, bf, acc1);
        s16x8 d0 = *(const s16x8*)&sxd[col][g * 32 + kq * 8];
        s16x8 d1 = *(const s16x8*)&sxd[16 + col][g * 32 + kq * 8];
        vac0 = MFMA16(d0, bf, vac0);
        vac1 = MFMA16(d1, bf, vac1);
    }
    int ic = isub + col;
    float bias = b0g[ic];
#pragma unroll
    for (int r = 0; r < 4; r++) {
        int bb = b0 + kq * 4 + r;
        float l1a = acc0[r] + bias;
        float dra = 1.f / (1.f + expf(-l1a));
        relu_b[bb * HH + ic] = f2bf(fmaxf(l1a, 0.f));
        drelu_f[bb * HH + ic] = dra;
        s0_b[bb * HH + ic] = f2bf(dra * vac0[r]);
        float l1b = acc1[r] + bias;
        float drb = 1.f / (1.f + expf(-l1b));
        relu_b[(bb + 16) * HH + ic] = f2bf(fmaxf(l1b, 0.f));
        drelu_f[(bb + 16) * HH + ic] = drb;
        s0_b[(bb + 16) * HH + ic] = f2bf(drb * vac1[r]);
    }
}

// ---------------------------------------------------------------------------
// k_th: z = relu@wout^T + b1 -> th=tanh(z), dtanh=1-th^2 (f32)
//       fused: curr0 = dtanh * (s0@wout^T)
//       stores curr0 as f32 row-major (h_dot init) and bf16 in A-FRAG layout
//       (the loop kernel's phase-0 input).
// ---------------------------------------------------------------------------
__global__ void k_th(const unsigned short* __restrict__ wop, const unsigned short* __restrict__ relu_b,
                     const unsigned short* __restrict__ s0_b, const float* __restrict__ b1g,
                     float* __restrict__ dtanh_f, unsigned short* __restrict__ curr_b,
                     float* __restrict__ curr0_f) {
    __shared__ unsigned short sr[32][520];
    __shared__ unsigned short ss0[32][520];
    int tid = threadIdx.x;
    int b0 = blockIdx.x * 32;
    int it = blockIdx.y;
    for (int idx = tid; idx < 32 * 64; idx += 256) {
        int r = idx >> 6, c8 = idx & 63;
        *(int4*)&sr[r][c8 * 8] = *(const int4*)&relu_b[(b0 + r) * HH + c8 * 8];
        *(int4*)&ss0[r][c8 * 8] = *(const int4*)&s0_b[(b0 + r) * HH + c8 * 8];
    }
    __syncthreads();
    int wv = tid >> 6, lane = tid & 63, col = lane & 15, kq = lane >> 4;
    int isub = it * 64 + wv * 16;
    int wpk = isub >> 5, cg = (isub >> 4) & 1;
    f32x4 acc0 = {0.f, 0.f, 0.f, 0.f}, acc1 = {0.f, 0.f, 0.f, 0.f};
    f32x4 cac0 = {0.f, 0.f, 0.f, 0.f}, cac1 = {0.f, 0.f, 0.f, 0.f};
    const s16x8* wofrag = (const s16x8*)wop + (size_t)((wpk * 2 + cg) * 16) * 64 + lane;
#pragma unroll
    for (int g = 0; g < 16; g++) {
        s16x8 bf = wofrag[g * 64];
        s16x8 a0 = *(const s16x8*)&sr[col][g * 32 + kq * 8];
        s16x8 a1 = *(const s16x8*)&sr[16 + col][g * 32 + kq * 8];
        acc0 = MFMA16(a0, bf, acc0);
        acc1 = MFMA16(a1, bf, acc1);
        s16x8 p0 = *(const s16x8*)&ss0[col][g * 32 + kq * 8];
        s16x8 p1 = *(const s16x8*)&ss0[16 + col][g * 32 + kq * 8];
        cac0 = MFMA16(p0, bf, cac0);
        cac1 = MFMA16(p1, bf, cac1);
    }
    int ic = isub + col;
    float bias = b1g[ic];
    // frag-layout column component: idx = t*8192 + (ic>>5)*512 + l*8 + (ic&7),
    // l = row + (((ic>>3)&3)<<4)  ->  fc = (ic>>5)*512 + (ic&7) + (((ic>>3)&3)<<7)
    int fc = (ic >> 5) * 512 + (ic & 7) + (((ic >> 3) & 3) << 7);
#pragma unroll
    for (int r = 0; r < 4; r++) {
        int bb = b0 + kq * 4 + r;
        int row8 = (kq * 4 + r) * 8;
        float th_a = tanhf(acc0[r] + bias);
        float dta = 1.f - th_a * th_a;
        float c0a = dta * cac0[r];
        dtanh_f[bb * HH + ic] = dta;
        curr_b[(bb >> 4) * 8192 + fc + row8] = f2bf(c0a);
        curr0_f[bb * HH + ic] = c0a;
        float th_b = tanhf(acc1[r] + bias);
        float dtb = 1.f - th_b * th_b;
        float c0b = dtb * cac1[r];
        dtanh_f[(bb + 16) * HH + ic] = dtb;
        curr_b[((bb + 16) >> 4) * 8192 + fc + row8] = f2bf(c0b);
        curr0_f[(bb + 16) * HH + ic] = c0b;
    }
}

// ---------------------------------------------------------------------------
// k_loop3: sync-free Neumann loop. One block per 16-row batch tile (16 blocks,
// 8 waves each). curr ping-pongs between two 16KB LDS A-frag buffers; the only
// per-phase sync is ONE __syncthreads. Weights are streamed from L2 every
// phase in MFMA-frag layout (512KB/phase/CU; each XCD's L2 caches the full
// 1MB wh+wout pair after phase 0 since blocks are 2-per-XCD under %8
// round-robin — correctness never depends on placement, only speed).
// Per wave: 4 output col-tiles (64 cols), depth-1 register double-buffer on
// the B-frag stream; 8 waves/CU keep 32-64KB of loads in flight.
// ---------------------------------------------------------------------------
__global__ __launch_bounds__(512) void k_loop3(
    const unsigned short* __restrict__ whp, const unsigned short* __restrict__ wop,
    const unsigned short* __restrict__ curr_b, const float* __restrict__ curr0_f,
    const float* __restrict__ drelu_f, const float* __restrict__ dtanh_f,
    float* __restrict__ outp) {
    __shared__ __align__(16) unsigned short sa[2][8192];  // ping-pong A-frag (16KB each)
    const int tid = threadIdx.x;
    const int w = tid >> 6, lane = tid & 63;
    const int col2 = lane & 15, kq = lane >> 4;
    const int bt = blockIdx.x;

    // stage curr0 tile (already A-frag layout from k_th) into sa[0]
    {
        const int4* src = (const int4*)(curr_b + (size_t)bt * 8192);
        int4* dst = (int4*)&sa[0][0];
        dst[tid] = src[tid];
        dst[tid + 512] = src[tid + 512];
    }

    // per-thread diagonals + h_dot accumulator: 4 col-tiles x 4 rows
    float dr[4][4], dt[4][4], hd[4][4];
#pragma unroll
    for (int t = 0; t < 4; t++) {
        const int c = (w * 4 + t) * 16 + col2;
#pragma unroll
        for (int r = 0; r < 4; r++) {
            const int row = bt * 16 + kq * 4 + r;
            dr[t][r] = drelu_f[row * HH + c];
            dt[t][r] = dtanh_f[row * HH + c];
            hd[t][r] = curr0_f[row * HH + c];
        }
    }

    // LDS halfword index (r=0) for writing my (row, col c) values in A-frag layout:
    //   pos(m, k) = (k>>5)*512 + (k&7) + (((k>>3)&3)<<7) + m*8,  m = kq*4+r
    int fb[4];
#pragma unroll
    for (int t = 0; t < 4; t++)
        fb[t] = ((w * 4 + t) >> 1) * 512 + (col2 & 7) + (((t * 2 + (col2 >> 3)) & 3) << 7) + kq * 32;

    // wave's B-frag base: tiles ct = w*4+t; frag (ct,g) at ((ct*16+g)*64+lane) s16x8
    const s16x8* wlh = (const s16x8*)whp + (size_t)w * 4096 + lane;
    const s16x8* wlo = (const s16x8*)wop + (size_t)w * 4096 + lane;
    const unsigned short* A0 = &sa[0][lane * 8];
    const unsigned short* A1 = &sa[1][lane * 8];

    __syncthreads();  // curr0 staged

    for (int p = 0; p < 16; p++) {
        const s16x8* wl = (p & 1) ? wlo : wlh;          // even: wh, odd: wout
        const unsigned short* Ar = (p & 1) ? A1 : A0;   // read sa[p&1]
        f32x4 acc[4] = {{0.f, 0.f, 0.f, 0.f}, {0.f, 0.f, 0.f, 0.f},
                        {0.f, 0.f, 0.f, 0.f}, {0.f, 0.f, 0.f, 0.f}};
        s16x8 bfr[2][4];
#pragma unroll
        for (int t = 0; t < 4; t++) bfr[0][t] = wl[t * 1024];
#pragma unroll
        for (int g = 0; g < 16; g++) {
            if (g < 15) {
#pragma unroll
                for (int t = 0; t < 4; t++) bfr[(g + 1) & 1][t] = wl[t * 1024 + (g + 1) * 64];
            }
            const s16x8 a = *(const s16x8*)(Ar + (size_t)g * 512);
#pragma unroll
            for (int t = 0; t < 4; t++) acc[t] = MFMA16(a, bfr[g & 1][t], acc[t]);
        }
        unsigned short* Aw = &sa[(p + 1) & 1][0];       // write the other buffer
        if (p & 1) {            // wout phase: curr' = dtanh*(s@wout^T); h_dot += curr'
            if (p < 15) {
#pragma unroll
                for (int t = 0; t < 4; t++)
#pragma unroll
                    for (int r = 0; r < 4; r++) {
                        float v = dt[t][r] * acc[t][r];
                        hd[t][r] += v;
                        Aw[fb[t] + r * 8] = f2bf(v);
                    }
            } else {
#pragma unroll
                for (int t = 0; t < 4; t++)
#pragma unroll
                    for (int r = 0; r < 4; r++) hd[t][r] += dt[t][r] * acc[t][r];
            }
        } else {                // wh phase: s = drelu*(curr@wh^T)
#pragma unroll
            for (int t = 0; t < 4; t++)
#pragma unroll
                for (int r = 0; r < 4; r++)
                    Aw[fb[t] + r * 8] = f2bf(dr[t][r] * acc[t][r]);
        }
        if (p < 15) __syncthreads();  // one barrier per phase (double-buffer => no lapping)
    }

#pragma unroll
    for (int t = 0; t < 4; t++) {
        const int c = (w * 4 + t) * 16 + col2;
#pragma unroll
        for (int r = 0; r < 4; r++)
            outp[(size_t)(bt * 16 + kq * 4 + r) * HH + c] = hd[t][r];
    }
}

// ---------------------------------------------------------------------------
extern "C" void kernel_launch(void* const* d_in, const int* in_sizes, int n_in,
                              void* d_out, int out_size, void* d_ws, size_t ws_size,
                              hipStream_t stream) {
    const float* tg = (const float*)d_in[0];
    const float* h = (const float*)d_in[1];
    const float* coeffs = (const float*)d_in[2];
    const float* dcoeffs = (const float*)d_in[3];
    const float* tobs = (const float*)d_in[4];
    const float* wx = (const float*)d_in[5];
    const float* wh = (const float*)d_in[6];
    const float* wout = (const float*)d_in[7];
    const float* b0g = (const float*)d_in[8];
    const float* b1g = (const float*)d_in[9];
    float* outp = (float*)d_out;

    char* ws = (char*)d_ws;
    unsigned short* whp    = (unsigned short*)(ws + 0);        // 512KB packed bf16
    unsigned short* wop    = (unsigned short*)(ws + 524288);   // 512KB
    unsigned short* wxp    = (unsigned short*)(ws + 1048576);  // 64KB
    unsigned short* hb     = (unsigned short*)(ws + 1114112);  // 256KB
    unsigned short* xb     = (unsigned short*)(ws + 1376256);  // 32KB
    unsigned short* xdb    = (unsigned short*)(ws + 1409024);  // 32KB
    unsigned short* relu_b = (unsigned short*)(ws + 1441792);  // 256KB
    unsigned short* s0_b   = (unsigned short*)(ws + 1703936);  // 256KB
    float* drelu_f         = (float*)(ws + 1966080);           // 512KB
    float* dtanh_f         = (float*)(ws + 2490368);           // 512KB
    unsigned short* curr_b = (unsigned short*)(ws + 3014656);  // 256KB (A-frag)
    float* curr0_f         = (float*)(ws + 3276800);           // 512KB
    unsigned int* cnt      = (unsigned int*)(ws + 4063232);    // 1KB (k_pack zeroes; unused by loop)

    k_pack<<<2753, 256, 0, stream>>>(wh, wout, wx, h, coeffs, dcoeffs, tobs, tg,
                                     whp, wop, wxp, hb, xb, xdb, cnt);
    k_l1<<<dim3(8, 8), 256, 0, stream>>>(whp, wxp, hb, xb, xdb, b0g, relu_b, drelu_f, s0_b);
    k_th<<<dim3(8, 8), 256, 0, stream>>>(wop, relu_b, s0_b, b1g, dtanh_f, curr_b, curr0_f);
    k_loop3<<<16, 512, 0, stream>>>(whp, wop, curr_b, curr0_f, drelu_f, dtanh_f, outp);
}